// Round 4
// baseline (866.715 us; speedup 1.0000x reference)
//
#include <hip/hip_runtime.h>
#include <cstdint>
#include <cstddef>

#define BATCH 4
#define NPT   8192
#define CH    256
#define KNN   16
#define BN_TOT (BATCH * NPT)   // 32768
#define CAP   64               // candidate cap per wave (4 waves/query)

// f32 distance for the conservative candidate filter only (rounding-order free)
__device__ __forceinline__ float dist2f(const float4 qp, const float4 cp) {
  float dot = qp.x * cp.x + qp.y * cp.y + qp.z * cp.z;
  return -2.0f * dot + qp.w + cp.w;
}

// np-matching f32 distance:
//   dot: numpy einsum dispatched scalar tail (count=3 < vstep), ascending,
//        gcc -O3 -ffp-contract=fast in FMA-dispatched TU -> ascending FMA chain.
//   then separate ufuncs: t = round(-2*dot); t = t + sn; t = t + sm.
__device__ __forceinline__ float dist2np(const float4 qp, const float4 cp) {
#pragma clang fp contract(off)
  float acc = qp.x * cp.x;                    // == fmaf(x,x',0)
  acc = __builtin_fmaf(qp.y, cp.y, acc);
  acc = __builtin_fmaf(qp.z, cp.z, acc);
  float t = -2.0f * acc;
  t = t + qp.w;
  t = t + cp.w;
  return t;
}

// ---------------- prep: cpack = (x,y,z,|p|^2), Wcat = [W1 | W2-W1]
// |p|^2 np-matching: src*src rounds each product into a temp array, then
// np.sum over n=3 sums ascending (pre-rounded products, no FMA possible).
__global__ __launch_bounds__(256) void prep_kernel(
    const float* __restrict__ q_pos, const float* __restrict__ W,
    float4* __restrict__ cpack, float* __restrict__ Wcat)
{
  int t = blockIdx.x * 256 + threadIdx.x;   // 0..131071
  {
    int k = t >> 9;
    int j = t & 511;
    float v;
    if (j < 256) {
      v = W[k * 256 + j];
    } else {
      int c = j - 256;
      v = W[(256 + k) * 256 + c] - W[k * 256 + c];
    }
    Wcat[t] = v;
  }
  if (t < BN_TOT) {
#pragma clang fp contract(off)
    float x = q_pos[3 * t + 0];
    float y = q_pos[3 * t + 1];
    float z = q_pos[3 * t + 2];
    float px = x * x;
    float py = y * y;
    float pz = z * z;
    float s = px + py;
    s = s + pz;
    cpack[t] = make_float4(x, y, z, s);
  }
}

// ---------------- knn pass: histogram + candidate collection (conservative superset)
// block = 256 thr = 4 waves; lane = query (64 queries/block); wave w scans candidate quarter w.
__global__ __launch_bounds__(256) void knn_kernel(
    const float4* __restrict__ cpack,
    unsigned short* __restrict__ qbufidx,  // [BN_TOT][4][CAP]
    unsigned int* __restrict__ qbufcnt)    // [BN_TOT][4]
{
  __shared__ unsigned short hist[4][64][33];  // [wave][query][bin], 33 = +1 pad
  __shared__ float edge_s[64];
  const int lane = threadIdx.x & 63;
  const int w    = threadIdx.x >> 6;
  const int b    = blockIdx.y;
  const int n    = blockIdx.x * 64 + lane;
  const int q    = b * NPT + n;

  unsigned short* myhist = &hist[w][lane][0];
#pragma unroll
  for (int i = 0; i < 33; ++i) myhist[i] = 0;

  const float4 qp = cpack[q];
  const float4* __restrict__ cb = cpack + b * NPT;
  const int m0 = w * (NPT / 4);

  // scan 1: half-octave histogram of distance float bits
  for (int m = m0; m < m0 + NPT / 4; ++m) {
    float4 cp = cb[m];                       // wave-uniform -> broadcast
    float d = dist2f(qp, cp);
    unsigned int bits = __float_as_uint(d);
    int bin = (int)(bits >> 22) - 240;       // bins cover d in [2^-7, 2^9)
    bin = bin < 0 ? 0 : (bin > 31 ? 31 : bin);
    bin = (d <= 0.0f) ? 0 : bin;             // negatives / exact zero -> bin 0
    myhist[bin] += 1;
  }
  __syncthreads();

  // merge 4 wave-histograms, find bin holding the 16th smallest
  if (threadIdx.x < 64) {
    int cum = 0;
    int B = 31;
#pragma unroll 1
    for (int bin = 0; bin < 32; ++bin) {
      cum += (int)hist[0][lane][bin] + (int)hist[1][lane][bin]
           + (int)hist[2][lane][bin] + (int)hist[3][lane][bin];
      if (cum >= KNN) { B = bin; break; }
    }
    // +1 extra half-octave of margin: any f32-variant / f64 skew (~1e-5 abs)
    // cannot exclude a true top-16 member (margin >= 0.19*d16 or >= 2^-7 abs).
    edge_s[lane] = __uint_as_float((unsigned int)(242 + B) << 22);
  }
  __syncthreads();

  // scan 2: collect candidate indices with d_f32 < edge (superset of exact top-16)
  const float edgef = edge_s[lane];
  unsigned int cnt = 0;
  unsigned short* mybuf = qbufidx + ((size_t)q * 4 + w) * CAP;
  for (int m = m0; m < m0 + NPT / 4; ++m) {
    float4 cp = cb[m];
    float d = dist2f(qp, cp);
    if (d < edgef) {
      if (cnt < CAP) mybuf[cnt] = (unsigned short)m;
      cnt++;
    }
  }
  qbufcnt[q * 4 + w] = cnt < (unsigned)CAP ? cnt : (unsigned)CAP;
}

// ---------------- finalize: np-matching f32 16th value + tie-exact selection (thread = query)
__global__ __launch_bounds__(256) void finalize_kernel(
    const float4* __restrict__ cpack,
    const unsigned short* __restrict__ qbufidx,
    const unsigned int* __restrict__ qbufcnt,
    int* __restrict__ idxout)
{
  __shared__ int outsl[256][17];
  const int tid = threadIdx.x;
  const int q = blockIdx.x * 256 + tid;
  const int b = q >> 13;
  const int nself = q & (NPT - 1);
  const float4 qp = cpack[q];
  const float4* __restrict__ cb = cpack + b * NPT;
  const unsigned short* __restrict__ buf = qbufidx + (size_t)q * (4 * CAP);
  int cw[4];
#pragma unroll
  for (int w = 0; w < 4; ++w) cw[w] = (int)qbufcnt[q * 4 + w];

  // safety init: self index (always a true near neighbor; avoids wild reads
  // downstream if any selection hole appears)
#pragma unroll
  for (int j = 0; j < 16; ++j) outsl[tid][j] = nself;

  // pass 1: 16th smallest np-f32 value over collected candidates
  float r[16];
#pragma unroll
  for (int i = 0; i < 16; ++i) r[i] = __builtin_inff();
#pragma unroll
  for (int w = 0; w < 4; ++w) {
    for (int i = 0; i < cw[w]; ++i) {
      int m = (int)buf[w * CAP + i];
      float d = dist2np(qp, cb[m]);
      if (d < r[15]) {
        float prev = -__builtin_inff();
#pragma unroll
        for (int j = 0; j < 16; ++j) {
          float rj = r[j];
          r[j] = fminf(fmaxf(prev, d), rj);
          prev = rj;
        }
      }
    }
  }
  const float T = r[15];

  // pass 2: all d<T (ascending index order) from the front; ties d==T fill
  // from the back (earliest-index ties win, matching stable top_k).
  int front = 0, tie_i = 0;
#pragma unroll
  for (int w = 0; w < 4; ++w) {
    for (int i = 0; i < cw[w]; ++i) {
      int m = (int)buf[w * CAP + i];
      float d = dist2np(qp, cb[m]);
      if (d < T) {
        outsl[tid][front] = m;
        front++;
      } else if (d == T) {
        int pos = 15 - tie_i;
        if (pos >= front) outsl[tid][pos] = m;
        tie_i++;
      }
    }
  }
#pragma unroll
  for (int j = 0; j < 16; ++j) idxout[(size_t)q * 16 + j] = outsl[tid][j];
}

// ---------------- fp32 tiled GEMM: [32768,256] @ [256,512] -> A (cols<256), Qn=d_out (cols>=256, +bias)
__global__ __launch_bounds__(256) void gemm_kernel(
    const float* __restrict__ Q, const float* __restrict__ Wcat,
    const float* __restrict__ bias,
    float* __restrict__ A, float* __restrict__ Qn)
{
  __shared__ float As[16][68];   // [k][m], padded
  __shared__ float Bs[16][64];   // [k][n]
  const int tid = threadIdx.x;
  const int tx = tid & 15, ty = tid >> 4;
  const int bm0 = blockIdx.x * 64;
  const int bn0 = blockIdx.y * 64;
  const int arow = tid >> 2, ac4 = (tid & 3) << 2;
  const int brow = tid >> 4, bc4 = (tid & 15) << 2;
  float acc[4][4];
#pragma unroll
  for (int i = 0; i < 4; ++i)
#pragma unroll
    for (int j = 0; j < 4; ++j) acc[i][j] = 0.0f;

  const float* aptr = Q + (size_t)(bm0 + arow) * 256 + ac4;
  const float* bptr = Wcat + (size_t)brow * 512 + bn0 + bc4;

  for (int k0 = 0; k0 < 256; k0 += 16) {
    float4 av = *(const float4*)(aptr + k0);
    float4 bv = *(const float4*)(bptr + (size_t)k0 * 512);
    __syncthreads();
    As[ac4 + 0][arow] = av.x;
    As[ac4 + 1][arow] = av.y;
    As[ac4 + 2][arow] = av.z;
    As[ac4 + 3][arow] = av.w;
    *(float4*)&Bs[brow][bc4] = bv;
    __syncthreads();
#pragma unroll
    for (int kk = 0; kk < 16; ++kk) {
      float4 a  = *(const float4*)&As[kk][ty * 4];
      float4 bb = *(const float4*)&Bs[kk][tx * 4];
      acc[0][0] += a.x * bb.x; acc[0][1] += a.x * bb.y; acc[0][2] += a.x * bb.z; acc[0][3] += a.x * bb.w;
      acc[1][0] += a.y * bb.x; acc[1][1] += a.y * bb.y; acc[1][2] += a.y * bb.z; acc[1][3] += a.y * bb.w;
      acc[2][0] += a.z * bb.x; acc[2][1] += a.z * bb.y; acc[2][2] += a.z * bb.z; acc[2][3] += a.z * bb.w;
      acc[3][0] += a.w * bb.x; acc[3][1] += a.w * bb.y; acc[3][2] += a.w * bb.z; acc[3][3] += a.w * bb.w;
    }
  }
#pragma unroll
  for (int rr = 0; rr < 4; ++rr) {
    int row = bm0 + ty * 4 + rr;
#pragma unroll
    for (int cc = 0; cc < 4; ++cc) {
      int j = bn0 + tx * 4 + cc;
      float v = acc[rr][cc];
      if (j < 256) A[(size_t)row * 256 + j] = v;
      else         Qn[(size_t)row * 256 + (j - 256)] = v + bias[j - 256];
    }
  }
}

// ---------------- gather + leaky + max; Out holds Qn on entry, overwritten with result
__global__ __launch_bounds__(256) void gather_kernel(
    const float* __restrict__ A, const int* __restrict__ idxout,
    float* __restrict__ Out)
{
  __shared__ int sidx[16];
  const int q = blockIdx.x;
  const int b = q >> 13;
  const int c = threadIdx.x;
  if (c < 16) sidx[c] = idxout[(size_t)q * 16 + c];
  __syncthreads();
  const float qn = Out[(size_t)q * 256 + c];
  const float* __restrict__ Ab = A + (size_t)b * NPT * 256;
  float best = -__builtin_inff();
#pragma unroll
  for (int j = 0; j < 16; ++j) {
    float a = Ab[(size_t)sidx[j] * 256 + c];
    float h = a + qn;
    best = fmaxf(best, fmaxf(h, 0.2f * h));   // leaky_relu(h, 0.2) == max(h, 0.2h)
  }
  Out[(size_t)q * 256 + c] = best;
}

extern "C" void kernel_launch(void* const* d_in, const int* in_sizes, int n_in,
                              void* d_out, int out_size, void* d_ws, size_t ws_size,
                              hipStream_t stream)
{
  (void)in_sizes; (void)n_in; (void)out_size; (void)ws_size;
  const float* qf   = (const float*)d_in[0];
  const float* qpos = (const float*)d_in[1];
  const float* W    = (const float*)d_in[2];
  const float* bias = (const float*)d_in[3];

  char* ws = (char*)d_ws;
  size_t off = 0;
  auto alloc = [&](size_t bytes) {
    void* p = ws + off;
    off += (bytes + 255) & ~(size_t)255;
    return p;
  };
  float4* cpack          = (float4*)alloc((size_t)BN_TOT * sizeof(float4));            // 512 KB
  float* Wcat            = (float*)alloc((size_t)256 * 512 * sizeof(float));           // 512 KB
  unsigned short* qbufidx= (unsigned short*)alloc((size_t)BN_TOT * 4 * CAP * 2);       // 16 MB
  unsigned int* qbufcnt  = (unsigned int*)alloc((size_t)BN_TOT * 4 * 4);               // 512 KB
  int* idxout            = (int*)alloc((size_t)BN_TOT * KNN * sizeof(int));            // 2 MB
  float* A               = (float*)alloc((size_t)BN_TOT * CH * sizeof(float));         // 32 MB
  float* Out             = (float*)d_out;                                              // Qn then result

  prep_kernel<<<512, 256, 0, stream>>>(qpos, W, cpack, Wcat);
  knn_kernel<<<dim3(128, BATCH), 256, 0, stream>>>(cpack, qbufidx, qbufcnt);
  finalize_kernel<<<128, 256, 0, stream>>>(cpack, qbufidx, qbufcnt, idxout);
  gemm_kernel<<<dim3(512, 8), 256, 0, stream>>>(qf, Wcat, bias, A, Out);
  gather_kernel<<<BN_TOT, 256, 0, stream>>>(A, idxout, Out);
}

// Round 5
// 502.838 us; speedup vs baseline: 1.7236x; 1.7236x over previous
//
#include <hip/hip_runtime.h>
#include <cstdint>
#include <cstddef>

#define BATCH 4
#define NPT   8192
#define CH    256
#define KNN   16
#define BN_TOT (BATCH * NPT)   // 32768
#define NSLICE 16              // candidate slices per query (one wave each)
#define SLICE  (NPT / NSLICE)  // 512
#define CAP    24              // candidate cap per (query, slice)

// f32 distance for the conservative candidate filter only (rounding-order free)
// np-matching f32 distance (DO NOT CHANGE — verified in R4):
//   dot: numpy einsum scalar tail (count=3), ascending FMA chain;
//   then separate ufuncs: t = round(-2*dot); t = t + sn; t = t + sm.
__device__ __forceinline__ float dist2np(const float4 qp, const float4 cp) {
#pragma clang fp contract(off)
  float acc = qp.x * cp.x;                    // == fmaf(x,x',0)
  acc = __builtin_fmaf(qp.y, cp.y, acc);
  acc = __builtin_fmaf(qp.z, cp.z, acc);
  float t = -2.0f * acc;
  t = t + qp.w;
  t = t + cp.w;
  return t;
}

// ---------------- prep: cpack = (x,y,z,|p|^2), Wcat = [W1 | W2-W1]
__global__ __launch_bounds__(256) void prep_kernel(
    const float* __restrict__ q_pos, const float* __restrict__ W,
    float4* __restrict__ cpack, float* __restrict__ Wcat)
{
  int t = blockIdx.x * 256 + threadIdx.x;   // 0..131071
  {
    int k = t >> 9;
    int j = t & 511;
    float v;
    if (j < 256) {
      v = W[k * 256 + j];
    } else {
      int c = j - 256;
      v = W[(256 + k) * 256 + c] - W[k * 256 + c];
    }
    Wcat[t] = v;
  }
  if (t < BN_TOT) {
#pragma clang fp contract(off)
    float x = q_pos[3 * t + 0];
    float y = q_pos[3 * t + 1];
    float z = q_pos[3 * t + 2];
    float px = x * x;
    float py = y * y;
    float pz = z * z;
    float s = px + py;
    s = s + pz;
    cpack[t] = make_float4(x, y, z, s);
  }
}

// ---------------- knn: 1024-thr blocks, 64 queries (lane = query), 16 waves = 16 candidate slices.
// Histogram: bin-pair-packed u32 (halves = even/odd bin), ds_add_u32, swizzled to spread banks.
__global__ __launch_bounds__(1024, 8) void knn_kernel(
    const float4* __restrict__ cpack,
    unsigned short* __restrict__ qbufidx,  // [BN_TOT][NSLICE][CAP]
    unsigned int* __restrict__ qbufcnt)    // [BN_TOT][NSLICE]
{
  __shared__ unsigned int hist[NSLICE][64][16];  // 64 KB: [slice][query][bin-pair dword]
  __shared__ unsigned short mcnt[64][32];        // merged per-query histogram
  __shared__ float edge_s[64];
  const int tid = threadIdx.x;
  const int l   = tid & 63;                      // query lane
  const int w   = __builtin_amdgcn_readfirstlane(tid >> 6);  // slice (wave-uniform SGPR)
  const int b   = blockIdx.y;
  const int q   = b * NPT + blockIdx.x * 64 + l;
  const int lh  = l >> 1;

  unsigned int* myh = &hist[w][l][0];
#pragma unroll
  for (int i = 0; i < 16; ++i) myh[i] = 0;
  __syncthreads();

  const float4 qp = cpack[q];
  const float m2x = -2.0f * qp.x, m2y = -2.0f * qp.y, m2z = -2.0f * qp.z;
  const float4* __restrict__ cb = cpack + b * NPT;
  const int m0 = w * SLICE;

  // scan 1: half-octave histogram of distance float bits (bins cover [2^-7, 2^9))
  for (int m = m0; m < m0 + SLICE; ++m) {
    float4 cp = cb[m];                           // wave-uniform -> scalar load
    float d = fmaf(m2z, cp.z, fmaf(m2y, cp.y, fmaf(m2x, cp.x, qp.w + cp.w)));
    int e = (__float_as_int(d) >> 22) - 241;     // arith shift: d<=0 -> negative -> bin 0
    int bin = min(max(e, 0), 31);
    unsigned int dw = ((unsigned)((bin >> 1) + lh)) & 15u;   // bank swizzle
    atomicAdd(&myh[dw], 1u << ((bin & 1) << 4));
  }
  __syncthreads();

  // merge 16 slice-histograms -> mcnt[query][bin]  (1024 thr x 2 pairs)
#pragma unroll
  for (int p = tid; p < 2048; p += 1024) {
    int qd = p >> 5, bb = p & 31;
    unsigned int dw = ((unsigned)((bb >> 1) + (qd >> 1))) & 15u;
    int sh = (bb & 1) << 4;
    unsigned int s = 0;
#pragma unroll
    for (int ww = 0; ww < NSLICE; ++ww) s += (hist[ww][qd][dw] >> sh) & 0xffffu;
    mcnt[qd][bb] = (unsigned short)s;
  }
  __syncthreads();

  // cumsum -> bin holding the 16th smallest; +1 extra half-octave margin so any
  // f32-rounding-variant skew cannot exclude a true top-16 member.
  if (tid < 64) {
    int cum = 0, B = 31;
#pragma unroll 1
    for (int bb = 0; bb < 32; ++bb) {
      cum += (int)mcnt[tid][bb];
      if (cum >= KNN) { B = bb; break; }
    }
    edge_s[tid] = __uint_as_float((unsigned)(242 + B) << 22);
  }
  __syncthreads();

  // scan 2: collect candidates with d < edge (conservative superset of top-16)
  const float edgef = edge_s[l];
  unsigned int cnt = 0;
  unsigned short* mybuf = qbufidx + ((size_t)q * NSLICE + w) * CAP;
  for (int m = m0; m < m0 + SLICE; ++m) {
    float4 cp = cb[m];
    float d = fmaf(m2z, cp.z, fmaf(m2y, cp.y, fmaf(m2x, cp.x, qp.w + cp.w)));
    if (d < edgef) {
      if (cnt < CAP) mybuf[cnt] = (unsigned short)m;
      cnt++;
    }
  }
  qbufcnt[q * NSLICE + w] = cnt < (unsigned)CAP ? cnt : (unsigned)CAP;
}

// ---------------- finalize: np-matching f32 16th value + tie-exact selection (thread = query)
__global__ __launch_bounds__(256) void finalize_kernel(
    const float4* __restrict__ cpack,
    const unsigned short* __restrict__ qbufidx,
    const unsigned int* __restrict__ qbufcnt,
    int* __restrict__ idxout)
{
  __shared__ int outsl[256][17];
  const int tid = threadIdx.x;
  const int q = blockIdx.x * 256 + tid;
  const int b = q >> 13;
  const int nself = q & (NPT - 1);
  const float4 qp = cpack[q];
  const float4* __restrict__ cb = cpack + b * NPT;
  const unsigned short* __restrict__ buf = qbufidx + (size_t)q * (NSLICE * CAP);

  // safety init: self index (always a true neighbor; avoids wild reads downstream)
#pragma unroll
  for (int j = 0; j < 16; ++j) outsl[tid][j] = nself;

  // pass 1: 16th smallest np-f32 value over collected candidates
  float r[16];
#pragma unroll
  for (int i = 0; i < 16; ++i) r[i] = __builtin_inff();
#pragma unroll 1
  for (int w = 0; w < NSLICE; ++w) {
    int cw = (int)qbufcnt[q * NSLICE + w];
    for (int i = 0; i < cw; ++i) {
      int m = (int)buf[w * CAP + i];
      float d = dist2np(qp, cb[m]);
      if (d < r[15]) {
        float prev = -__builtin_inff();
#pragma unroll
        for (int j = 0; j < 16; ++j) {
          float rj = r[j];
          r[j] = fminf(fmaxf(prev, d), rj);
          prev = rj;
        }
      }
    }
  }
  const float T = r[15];

  // pass 2: all d<T (ascending index order) from the front; ties d==T fill
  // from the back (earliest-index ties win, matching stable top_k).
  int front = 0, tie_i = 0;
#pragma unroll 1
  for (int w = 0; w < NSLICE; ++w) {
    int cw = (int)qbufcnt[q * NSLICE + w];
    for (int i = 0; i < cw; ++i) {
      int m = (int)buf[w * CAP + i];
      float d = dist2np(qp, cb[m]);
      if (d < T) {
        outsl[tid][front] = m;
        front++;
      } else if (d == T) {
        int pos = 15 - tie_i;
        if (pos >= front) outsl[tid][pos] = m;
        tie_i++;
      }
    }
  }
#pragma unroll
  for (int j = 0; j < 16; ++j) idxout[(size_t)q * 16 + j] = outsl[tid][j];
}

// ---------------- fp32 tiled GEMM: [32768,256] @ [256,512] -> A (cols<256), Qn=d_out (cols>=256, +bias)
__global__ __launch_bounds__(256) void gemm_kernel(
    const float* __restrict__ Q, const float* __restrict__ Wcat,
    const float* __restrict__ bias,
    float* __restrict__ A, float* __restrict__ Qn)
{
  __shared__ float As[16][68];   // [k][m], padded
  __shared__ float Bs[16][64];   // [k][n]
  const int tid = threadIdx.x;
  const int tx = tid & 15, ty = tid >> 4;
  const int bm0 = blockIdx.x * 64;
  const int bn0 = blockIdx.y * 64;
  const int arow = tid >> 2, ac4 = (tid & 3) << 2;
  const int brow = tid >> 4, bc4 = (tid & 15) << 2;
  float acc[4][4];
#pragma unroll
  for (int i = 0; i < 4; ++i)
#pragma unroll
    for (int j = 0; j < 4; ++j) acc[i][j] = 0.0f;

  const float* aptr = Q + (size_t)(bm0 + arow) * 256 + ac4;
  const float* bptr = Wcat + (size_t)brow * 512 + bn0 + bc4;

  for (int k0 = 0; k0 < 256; k0 += 16) {
    float4 av = *(const float4*)(aptr + k0);
    float4 bv = *(const float4*)(bptr + (size_t)k0 * 512);
    __syncthreads();
    As[ac4 + 0][arow] = av.x;
    As[ac4 + 1][arow] = av.y;
    As[ac4 + 2][arow] = av.z;
    As[ac4 + 3][arow] = av.w;
    *(float4*)&Bs[brow][bc4] = bv;
    __syncthreads();
#pragma unroll
    for (int kk = 0; kk < 16; ++kk) {
      float4 a  = *(const float4*)&As[kk][ty * 4];
      float4 bb = *(const float4*)&Bs[kk][tx * 4];
      acc[0][0] += a.x * bb.x; acc[0][1] += a.x * bb.y; acc[0][2] += a.x * bb.z; acc[0][3] += a.x * bb.w;
      acc[1][0] += a.y * bb.x; acc[1][1] += a.y * bb.y; acc[1][2] += a.y * bb.z; acc[1][3] += a.y * bb.w;
      acc[2][0] += a.z * bb.x; acc[2][1] += a.z * bb.y; acc[2][2] += a.z * bb.z; acc[2][3] += a.z * bb.w;
      acc[3][0] += a.w * bb.x; acc[3][1] += a.w * bb.y; acc[3][2] += a.w * bb.z; acc[3][3] += a.w * bb.w;
    }
  }
#pragma unroll
  for (int rr = 0; rr < 4; ++rr) {
    int row = bm0 + ty * 4 + rr;
#pragma unroll
    for (int cc = 0; cc < 4; ++cc) {
      int j = bn0 + tx * 4 + cc;
      float v = acc[rr][cc];
      if (j < 256) A[(size_t)row * 256 + j] = v;
      else         Qn[(size_t)row * 256 + (j - 256)] = v + bias[j - 256];
    }
  }
}

// ---------------- gather + leaky + max; Out holds Qn on entry, overwritten with result
__global__ __launch_bounds__(256) void gather_kernel(
    const float* __restrict__ A, const int* __restrict__ idxout,
    float* __restrict__ Out)
{
  __shared__ int sidx[16];
  const int q = blockIdx.x;
  const int b = q >> 13;
  const int c = threadIdx.x;
  if (c < 16) sidx[c] = idxout[(size_t)q * 16 + c];
  __syncthreads();
  const float qn = Out[(size_t)q * 256 + c];
  const float* __restrict__ Ab = A + (size_t)b * NPT * 256;
  float best = -__builtin_inff();
#pragma unroll
  for (int j = 0; j < 16; ++j) {
    float a = Ab[(size_t)sidx[j] * 256 + c];
    float h = a + qn;
    best = fmaxf(best, fmaxf(h, 0.2f * h));   // leaky_relu(h, 0.2) == max(h, 0.2h)
  }
  Out[(size_t)q * 256 + c] = best;
}

extern "C" void kernel_launch(void* const* d_in, const int* in_sizes, int n_in,
                              void* d_out, int out_size, void* d_ws, size_t ws_size,
                              hipStream_t stream)
{
  (void)in_sizes; (void)n_in; (void)out_size; (void)ws_size;
  const float* qf   = (const float*)d_in[0];
  const float* qpos = (const float*)d_in[1];
  const float* W    = (const float*)d_in[2];
  const float* bias = (const float*)d_in[3];

  char* ws = (char*)d_ws;
  size_t off = 0;
  auto alloc = [&](size_t bytes) {
    void* p = ws + off;
    off += (bytes + 255) & ~(size_t)255;
    return p;
  };
  float4* cpack          = (float4*)alloc((size_t)BN_TOT * sizeof(float4));              // 512 KB
  float* Wcat            = (float*)alloc((size_t)256 * 512 * sizeof(float));             // 512 KB
  unsigned int* qbufcnt  = (unsigned int*)alloc((size_t)BN_TOT * NSLICE * 4);            // 2 MB
  int* idxout            = (int*)alloc((size_t)BN_TOT * KNN * sizeof(int));              // 2 MB
  // shared region: qbufidx (24 MB) is dead after finalize; A (32 MB) written by gemm after.
  void* shared_region    = alloc((size_t)BN_TOT * CH * sizeof(float));                   // 32 MB
  unsigned short* qbufidx= (unsigned short*)shared_region;
  float* A               = (float*)shared_region;
  float* Out             = (float*)d_out;                                                // Qn then result

  prep_kernel<<<512, 256, 0, stream>>>(qpos, W, cpack, Wcat);
  knn_kernel<<<dim3(128, BATCH), 1024, 0, stream>>>(cpack, qbufidx, qbufcnt);
  finalize_kernel<<<128, 256, 0, stream>>>(cpack, qbufidx, qbufcnt, idxout);
  gemm_kernel<<<dim3(512, 8), 256, 0, stream>>>(qf, Wcat, bias, A, Out);
  gather_kernel<<<BN_TOT, 256, 0, stream>>>(A, idxout, Out);
}

// Round 7
// 416.356 us; speedup vs baseline: 2.0817x; 1.2077x over previous
//
#include <hip/hip_runtime.h>
#include <hip/hip_bf16.h>
#include <cstdint>
#include <cstddef>

#define BATCH 4
#define NPT   8192
#define CH    256
#define KNN   16
#define BN_TOT (BATCH * NPT)   // 32768
#define NSLICE 16              // candidate slices per query (one wave each)
#define SLICE  (NPT / NSLICE)  // 512
#define CAP    24              // candidate cap per (query, slice)

typedef __attribute__((ext_vector_type(8))) short bf16x8;
typedef __attribute__((ext_vector_type(4))) float f32x4;

// np-matching f32 distance (DO NOT CHANGE — verified in R4):
//   dot: numpy einsum scalar tail (count=3), ascending FMA chain;
//   then separate ufuncs: t = round(-2*dot); t = t + sn; t = t + sm.
__device__ __forceinline__ float dist2np(const float4 qp, const float4 cp) {
#pragma clang fp contract(off)
  float acc = qp.x * cp.x;                    // == fmaf(x,x',0)
  acc = __builtin_fmaf(qp.y, cp.y, acc);
  acc = __builtin_fmaf(qp.z, cp.z, acc);
  float t = -2.0f * acc;
  t = t + qp.w;
  t = t + cp.w;
  return t;
}

__device__ __forceinline__ unsigned int pk_bf16(float a, float b) {
  __hip_bfloat162 h = __float22bfloat162_rn(make_float2(a, b));
  return *(unsigned int*)&h;
}

// ---------------- prep: cpack = (x,y,z,|p|^2), WbT[n][k] = bf16([W1 | W2-W1]^T)
__global__ __launch_bounds__(256) void prep_kernel(
    const float* __restrict__ q_pos, const float* __restrict__ W,
    float4* __restrict__ cpack, unsigned short* __restrict__ WbT)
{
  int t = blockIdx.x * 256 + threadIdx.x;   // 0..131071
  {
    int k = t >> 9;
    int j = t & 511;
    float v;
    if (j < 256) {
      v = W[k * 256 + j];
    } else {
      int c = j - 256;
      v = W[(256 + k) * 256 + c] - W[k * 256 + c];
    }
    __hip_bfloat16 hb = __float2bfloat16(v);       // RNE
    WbT[(size_t)j * 256 + k] = *(unsigned short*)&hb;
  }
  if (t < BN_TOT) {
#pragma clang fp contract(off)
    float x = q_pos[3 * t + 0];
    float y = q_pos[3 * t + 1];
    float z = q_pos[3 * t + 2];
    float px = x * x;
    float py = y * y;
    float pz = z * z;
    float s = px + py;
    s = s + pz;
    cpack[t] = make_float4(x, y, z, s);
  }
}

// ---------------- knn: 1024-thr blocks, 64 queries (lane = query), 16 waves = 16 candidate slices.
__global__ __launch_bounds__(1024, 8) void knn_kernel(
    const float4* __restrict__ cpack,
    unsigned short* __restrict__ qbufidx,  // [BN_TOT][NSLICE][CAP]
    unsigned int* __restrict__ qbufcnt)    // [BN_TOT][NSLICE]
{
  __shared__ unsigned int hist[NSLICE][64][16];  // 64 KB: [slice][query][bin-pair dword]
  __shared__ unsigned short mcnt[64][32];        // merged per-query histogram
  __shared__ float edge_s[64];
  const int tid = threadIdx.x;
  const int l   = tid & 63;                      // query lane
  const int w   = __builtin_amdgcn_readfirstlane(tid >> 6);  // slice (wave-uniform SGPR)
  const int b   = blockIdx.y;
  const int q   = b * NPT + blockIdx.x * 64 + l;
  const int lh  = l >> 1;

  unsigned int* myh = &hist[w][l][0];
#pragma unroll
  for (int i = 0; i < 16; ++i) myh[i] = 0;
  __syncthreads();

  const float4 qp = cpack[q];
  const float m2x = -2.0f * qp.x, m2y = -2.0f * qp.y, m2z = -2.0f * qp.z;
  const float4* __restrict__ cb = cpack + b * NPT;
  const int m0 = w * SLICE;

  // scan 1: half-octave histogram of distance float bits (bins cover [2^-7, 2^9))
  for (int m = m0; m < m0 + SLICE; ++m) {
    float4 cp = cb[m];                           // wave-uniform -> scalar load
    float d = fmaf(m2z, cp.z, fmaf(m2y, cp.y, fmaf(m2x, cp.x, qp.w + cp.w)));
    int e = (__float_as_int(d) >> 22) - 241;     // arith shift: d<=0 -> negative -> bin 0
    int bin = min(max(e, 0), 31);
    unsigned int dw = ((unsigned)((bin >> 1) + lh)) & 15u;   // bank swizzle
    atomicAdd(&myh[dw], 1u << ((bin & 1) << 4));
  }
  __syncthreads();

  // merge 16 slice-histograms -> mcnt[query][bin]
#pragma unroll
  for (int p = tid; p < 2048; p += 1024) {
    int qd = p >> 5, bb = p & 31;
    unsigned int dw = ((unsigned)((bb >> 1) + (qd >> 1))) & 15u;
    int sh = (bb & 1) << 4;
    unsigned int s = 0;
#pragma unroll
    for (int ww = 0; ww < NSLICE; ++ww) s += (hist[ww][qd][dw] >> sh) & 0xffffu;
    mcnt[qd][bb] = (unsigned short)s;
  }
  __syncthreads();

  // cumsum -> bin holding the 16th smallest; +1 extra half-octave conservative margin
  if (tid < 64) {
    int cum = 0, B = 31;
#pragma unroll 1
    for (int bb = 0; bb < 32; ++bb) {
      cum += (int)mcnt[tid][bb];
      if (cum >= KNN) { B = bb; break; }
    }
    edge_s[tid] = __uint_as_float((unsigned)(242 + B) << 22);
  }
  __syncthreads();

  // scan 2: collect candidates with d < edge (conservative superset of top-16)
  const float edgef = edge_s[l];
  unsigned int cnt = 0;
  unsigned short* mybuf = qbufidx + ((size_t)q * NSLICE + w) * CAP;
  for (int m = m0; m < m0 + SLICE; ++m) {
    float4 cp = cb[m];
    float d = fmaf(m2z, cp.z, fmaf(m2y, cp.y, fmaf(m2x, cp.x, qp.w + cp.w)));
    if (d < edgef) {
      if (cnt < CAP) mybuf[cnt] = (unsigned short)m;
      cnt++;
    }
  }
  qbufcnt[q * NSLICE + w] = cnt < (unsigned)CAP ? cnt : (unsigned)CAP;
}

// ---------------- finalize: np-matching f32 16th value + tie-exact selection (thread = query)
__global__ __launch_bounds__(256) void finalize_kernel(
    const float4* __restrict__ cpack,
    const unsigned short* __restrict__ qbufidx,
    const unsigned int* __restrict__ qbufcnt,
    int* __restrict__ idxout)
{
  __shared__ int outsl[256][17];
  const int tid = threadIdx.x;
  const int q = blockIdx.x * 256 + tid;
  const int b = q >> 13;
  const int nself = q & (NPT - 1);
  const float4 qp = cpack[q];
  const float4* __restrict__ cb = cpack + b * NPT;
  const unsigned short* __restrict__ buf = qbufidx + (size_t)q * (NSLICE * CAP);

#pragma unroll
  for (int j = 0; j < 16; ++j) outsl[tid][j] = nself;

  float r[16];
#pragma unroll
  for (int i = 0; i < 16; ++i) r[i] = __builtin_inff();
#pragma unroll 1
  for (int w = 0; w < NSLICE; ++w) {
    int cw = (int)qbufcnt[q * NSLICE + w];
    for (int i = 0; i < cw; ++i) {
      int m = (int)buf[w * CAP + i];
      float d = dist2np(qp, cb[m]);
      if (d < r[15]) {
        float prev = -__builtin_inff();
#pragma unroll
        for (int j = 0; j < 16; ++j) {
          float rj = r[j];
          r[j] = fminf(fmaxf(prev, d), rj);
          prev = rj;
        }
      }
    }
  }
  const float T = r[15];

  int front = 0, tie_i = 0;
#pragma unroll 1
  for (int w = 0; w < NSLICE; ++w) {
    int cw = (int)qbufcnt[q * NSLICE + w];
    for (int i = 0; i < cw; ++i) {
      int m = (int)buf[w * CAP + i];
      float d = dist2np(qp, cb[m]);
      if (d < T) {
        outsl[tid][front] = m;
        front++;
      } else if (d == T) {
        int pos = 15 - tie_i;
        if (pos >= front) outsl[tid][pos] = m;
        tie_i++;
      }
    }
  }
#pragma unroll
  for (int j = 0; j < 16; ++j) idxout[(size_t)q * 16 + j] = outsl[tid][j];
}

// ---------------- bf16 MFMA GEMM: Qf32[32768,256] x WbT[512,256]^T -> A (n<256), Qn=d_out (n>=256,+bias)
// 128x128 block tile, 4 waves in 2x2, 64x64 per wave, 16x16x32 mfma, K=256 in 8 steps.
#define ASTRIDE 40   // LDS row stride in bf16 elems (80 B, 16B-aligned, odd dword count)
__global__ __launch_bounds__(256) void gemm_kernel(
    const float* __restrict__ Q, const unsigned short* __restrict__ WbT,
    const float* __restrict__ bias,
    float* __restrict__ A, float* __restrict__ Qn)
{
  __shared__ __align__(16) unsigned short As[128 * ASTRIDE];
  __shared__ __align__(16) unsigned short Bs[128 * ASTRIDE];
  const int tid  = threadIdx.x;
  const int lane = tid & 63;
  const int wv   = tid >> 6;
  const int wr   = wv & 1, wc = wv >> 1;
  const int bm0  = blockIdx.x * 128;
  const int bn0  = blockIdx.y * 128;
  const int srow = tid >> 1;           // staging row 0..127
  const int skh  = tid & 1;            // staging k-half (16 elems)
  const int quad = lane >> 4;
  const int l15  = lane & 15;

  f32x4 acc[4][4];
#pragma unroll
  for (int i = 0; i < 4; ++i)
#pragma unroll
    for (int j = 0; j < 4; ++j) acc[i][j] = (f32x4)0.0f;

  const float* ag = Q + (size_t)(bm0 + srow) * 256 + skh * 16;
  const unsigned short* bg = WbT + (size_t)(bn0 + srow) * 256 + skh * 16;
  unsigned short* asw = &As[srow * ASTRIDE + skh * 16];
  unsigned short* bsw = &Bs[srow * ASTRIDE + skh * 16];

  for (int k0 = 0; k0 < 256; k0 += 32) {
    // stage A (f32 -> bf16 RNE, 16 elems = 4 float4) and B (bf16, 16 elems = 2 uint4)
    float4 f0 = *(const float4*)(ag + k0);
    float4 f1 = *(const float4*)(ag + k0 + 4);
    float4 f2 = *(const float4*)(ag + k0 + 8);
    float4 f3 = *(const float4*)(ag + k0 + 12);
    uint4 bv0 = *(const uint4*)(bg + k0);        // k-local [0,8)
    uint4 bv1 = *(const uint4*)(bg + k0 + 8);    // k-local [8,16)  (R6 bug: was missing)
    uint4 a0, a1;
    a0.x = pk_bf16(f0.x, f0.y); a0.y = pk_bf16(f0.z, f0.w);
    a0.z = pk_bf16(f1.x, f1.y); a0.w = pk_bf16(f1.z, f1.w);
    a1.x = pk_bf16(f2.x, f2.y); a1.y = pk_bf16(f2.z, f2.w);
    a1.z = pk_bf16(f3.x, f3.y); a1.w = pk_bf16(f3.z, f3.w);
    __syncthreads();
    *(uint4*)(asw) = a0;
    *(uint4*)(asw + 8) = a1;
    *(uint4*)(bsw) = bv0;
    *(uint4*)(bsw + 8) = bv1;
    __syncthreads();

    // frags + mfma
    bf16x8 af[4], bf[4];
#pragma unroll
    for (int rt = 0; rt < 4; ++rt)
      af[rt] = *(const bf16x8*)&As[(wr * 64 + rt * 16 + l15) * ASTRIDE + quad * 8];
#pragma unroll
    for (int ct = 0; ct < 4; ++ct)
      bf[ct] = *(const bf16x8*)&Bs[(wc * 64 + ct * 16 + l15) * ASTRIDE + quad * 8];
#pragma unroll
    for (int rt = 0; rt < 4; ++rt)
#pragma unroll
      for (int ct = 0; ct < 4; ++ct)
        acc[rt][ct] = __builtin_amdgcn_mfma_f32_16x16x32_bf16(af[rt], bf[ct], acc[rt][ct], 0, 0, 0);
  }

  // epilogue: C/D layout col=lane&15, row=quad*4+reg (verified m89/m91)
  if (bn0 < 256) {
#pragma unroll
    for (int ct = 0; ct < 4; ++ct) {
      int col = bn0 + wc * 64 + ct * 16 + l15;
#pragma unroll
      for (int rt = 0; rt < 4; ++rt) {
        int rowb = bm0 + wr * 64 + rt * 16 + quad * 4;
#pragma unroll
        for (int r = 0; r < 4; ++r)
          A[(size_t)(rowb + r) * 256 + col] = acc[rt][ct][r];
      }
    }
  } else {
#pragma unroll
    for (int ct = 0; ct < 4; ++ct) {
      int col = bn0 + wc * 64 + ct * 16 + l15 - 256;
      float bvl = bias[col];
#pragma unroll
      for (int rt = 0; rt < 4; ++rt) {
        int rowb = bm0 + wr * 64 + rt * 16 + quad * 4;
#pragma unroll
        for (int r = 0; r < 4; ++r)
          Qn[(size_t)(rowb + r) * 256 + col] = acc[rt][ct][r] + bvl;
      }
    }
  }
}

// ---------------- gather + leaky + max; Out holds Qn on entry, overwritten with result
__global__ __launch_bounds__(256) void gather_kernel(
    const float* __restrict__ A, const int* __restrict__ idxout,
    float* __restrict__ Out)
{
  __shared__ int sidx[16];
  const int q = blockIdx.x;
  const int b = q >> 13;
  const int c = threadIdx.x;
  if (c < 16) sidx[c] = idxout[(size_t)q * 16 + c];
  __syncthreads();
  const float qn = Out[(size_t)q * 256 + c];
  const float* __restrict__ Ab = A + (size_t)b * NPT * 256;
  float best = -__builtin_inff();
#pragma unroll
  for (int j = 0; j < 16; ++j) {
    float a = Ab[(size_t)sidx[j] * 256 + c];
    float h = a + qn;
    best = fmaxf(best, fmaxf(h, 0.2f * h));   // leaky_relu(h, 0.2) == max(h, 0.2h)
  }
  Out[(size_t)q * 256 + c] = best;
}

extern "C" void kernel_launch(void* const* d_in, const int* in_sizes, int n_in,
                              void* d_out, int out_size, void* d_ws, size_t ws_size,
                              hipStream_t stream)
{
  (void)in_sizes; (void)n_in; (void)out_size; (void)ws_size;
  const float* qf   = (const float*)d_in[0];
  const float* qpos = (const float*)d_in[1];
  const float* W    = (const float*)d_in[2];
  const float* bias = (const float*)d_in[3];

  char* ws = (char*)d_ws;
  size_t off = 0;
  auto alloc = [&](size_t bytes) {
    void* p = ws + off;
    off += (bytes + 255) & ~(size_t)255;
    return p;
  };
  float4* cpack          = (float4*)alloc((size_t)BN_TOT * sizeof(float4));              // 512 KB
  unsigned short* WbT    = (unsigned short*)alloc((size_t)512 * 256 * 2);                // 256 KB
  unsigned int* qbufcnt  = (unsigned int*)alloc((size_t)BN_TOT * NSLICE * 4);            // 2 MB
  int* idxout            = (int*)alloc((size_t)BN_TOT * KNN * sizeof(int));              // 2 MB
  // shared region: qbufidx (24 MB) dead after finalize; A (32 MB) written by gemm after.
  void* shared_region    = alloc((size_t)BN_TOT * CH * sizeof(float));                   // 32 MB
  unsigned short* qbufidx= (unsigned short*)shared_region;
  float* A               = (float*)shared_region;
  float* Out             = (float*)d_out;                                                // Qn then result

  prep_kernel<<<512, 256, 0, stream>>>(qpos, W, cpack, WbT);
  knn_kernel<<<dim3(128, BATCH), 1024, 0, stream>>>(cpack, qbufidx, qbufcnt);
  finalize_kernel<<<128, 256, 0, stream>>>(cpack, qbufidx, qbufcnt, idxout);
  gemm_kernel<<<dim3(256, 4), 256, 0, stream>>>(qf, WbT, bias, A, Out);
  gather_kernel<<<BN_TOT, 256, 0, stream>>>(A, idxout, Out);
}

// Round 10
// 363.749 us; speedup vs baseline: 2.3827x; 1.1446x over previous
//
#include <hip/hip_runtime.h>
#include <hip/hip_bf16.h>
#include <cstdint>
#include <cstddef>

#define BATCH 4
#define NPT   8192
#define CH    256
#define KNN   16
#define BN_TOT (BATCH * NPT)   // 32768
#define NSLICE 16              // candidate slices per query (one wave each)
#define SLICE  (NPT / NSLICE)  // 512
#define CAP    32              // candidate cap per (query, slice) in LDS (64 KB)

typedef __attribute__((ext_vector_type(8))) short bf16x8;
typedef __attribute__((ext_vector_type(4))) float f32x4;

// np-matching f32 distance (DO NOT CHANGE — verified in R4):
//   dot: numpy einsum scalar tail (count=3), ascending FMA chain;
//   then separate ufuncs: t = round(-2*dot); t = t + sn; t = t + sm.
__device__ __forceinline__ float dist2np(const float4 qp, const float4 cp) {
#pragma clang fp contract(off)
  float acc = qp.x * cp.x;                    // == fmaf(x,x',0)
  acc = __builtin_fmaf(qp.y, cp.y, acc);
  acc = __builtin_fmaf(qp.z, cp.z, acc);
  float t = -2.0f * acc;
  t = t + qp.w;
  t = t + cp.w;
  return t;
}

__device__ __forceinline__ unsigned int pk_bf16(float a, float b) {
  __hip_bfloat162 h = __float22bfloat162_rn(make_float2(a, b));
  return *(unsigned int*)&h;
}

// ---------------- prep: cpack = (x,y,z,|p|^2), WbT[n][k] = bf16([W1 | W2-W1]^T)
__global__ __launch_bounds__(256) void prep_kernel(
    const float* __restrict__ q_pos, const float* __restrict__ W,
    float4* __restrict__ cpack, unsigned short* __restrict__ WbT)
{
  int t = blockIdx.x * 256 + threadIdx.x;   // 0..131071
  {
    int k = t >> 9;
    int j = t & 511;
    float v;
    if (j < 256) {
      v = W[k * 256 + j];
    } else {
      int c = j - 256;
      v = W[(256 + k) * 256 + c] - W[k * 256 + c];
    }
    __hip_bfloat16 hb = __float2bfloat16(v);       // RNE
    WbT[(size_t)j * 256 + k] = *(unsigned short*)&hb;
  }
  if (t < BN_TOT) {
#pragma clang fp contract(off)
    float x = q_pos[3 * t + 0];
    float y = q_pos[3 * t + 1];
    float z = q_pos[3 * t + 2];
    float px = x * x;
    float py = y * y;
    float pz = z * z;
    float s = px + py;
    s = s + pz;
    cpack[t] = make_float4(x, y, z, s);
  }
}

// ---------------- knn (all-in-one): FULL-sample histogram -> tight edge (242+B,
// R5/R7-proven; wider edges overflow CAP on outlier queries — R8/R9 post-mortem)
// -> collect to LDS -> inline exact selection by wave 0.
// 1024-thr blocks: 64 queries (lane = query), 16 waves = 16 candidate slices.
__global__ __launch_bounds__(1024, 8) void knn_kernel(
    const float4* __restrict__ cpack,
    int* __restrict__ idxout)
{
  __shared__ unsigned int histbuf[NSLICE][64][16]; // 64 KB; reused as candidate store after merge
  __shared__ unsigned short mcnt[64][32];          // merged per-query histogram (4 KB)
  __shared__ unsigned short scnt[NSLICE][64];      // per (slice,query) candidate count (2 KB)
  __shared__ float edge_s[64];
  __shared__ int outs[64][17];                     // phase-3 output staging
  unsigned short* cand = (unsigned short*)histbuf; // [NSLICE][64][CAP] u16 = 64 KB exactly

  const int tid = threadIdx.x;
  const int l   = tid & 63;                        // query lane
  const int w   = __builtin_amdgcn_readfirstlane(tid >> 6);  // slice (wave-uniform)
  const int b   = blockIdx.y;
  const int q   = b * NPT + blockIdx.x * 64 + l;
  const int lh  = l >> 1;

  unsigned int* myh = &histbuf[w][l][0];
#pragma unroll
  for (int i = 0; i < 16; ++i) myh[i] = 0;
  __syncthreads();

  const float4 qp = cpack[q];
  const float m2x = -2.0f * qp.x, m2y = -2.0f * qp.y, m2z = -2.0f * qp.z;
  const float4* __restrict__ cb = cpack + b * NPT;
  const int m0 = w * SLICE;

  // scan 1 (FULL sample): half-octave histogram of fast-d float bits
  for (int m = m0; m < m0 + SLICE; ++m) {
    float4 cp = cb[m];                           // wave-uniform -> scalar load
    float d = fmaf(m2z, cp.z, fmaf(m2y, cp.y, fmaf(m2x, cp.x, qp.w + cp.w)));
    int e = (__float_as_int(d) >> 22) - 241;     // arith shift: d<=0 -> bin 0
    int bin = min(max(e, 0), 31);
    unsigned int dw = ((unsigned)((bin >> 1) + lh)) & 15u;   // bank swizzle
    atomicAdd(&myh[dw], 1u << ((bin & 1) << 4));
  }
  __syncthreads();

  // merge 16 slice-histograms -> mcnt[query][bin]
#pragma unroll
  for (int p = tid; p < 2048; p += 1024) {
    int qd = p >> 5, bb = p & 31;
    unsigned int dw = ((unsigned)((bb >> 1) + (qd >> 1))) & 15u;
    int sh = (bb & 1) << 4;
    unsigned int s = 0;
#pragma unroll
    for (int ww = 0; ww < NSLICE; ++ww) s += (histbuf[ww][qd][dw] >> sh) & 0xffffu;
    mcnt[qd][bb] = (unsigned short)s;
  }
  __syncthreads();

  // cumsum -> bin B holding the 16th smallest; edge = upper(B) (R5/R7-proven)
  if (tid < 64) {
    int cum = 0, B = 31;
#pragma unroll 1
    for (int bb = 0; bb < 32; ++bb) {
      cum += (int)mcnt[tid][bb];
      if (cum >= KNN) { B = bb; break; }
    }
    edge_s[tid] = __uint_as_float((unsigned)(242 + B) << 22);
  }
  __syncthreads();   // histbuf dead from here; scan2 reuses it as cand

  // scan 2 (full): collect candidates with d < edge into LDS
  const float edgef = edge_s[l];
  unsigned int cnt = 0;
  unsigned short* mybuf = &cand[(w * 64 + l) * CAP];
  for (int m = m0; m < m0 + SLICE; ++m) {
    float4 cp = cb[m];
    float d = fmaf(m2z, cp.z, fmaf(m2y, cp.y, fmaf(m2x, cp.x, qp.w + cp.w)));
    if (d < edgef) {
      if (cnt < CAP) mybuf[cnt] = (unsigned short)m;
      cnt++;
    }
  }
  scnt[w][l] = (unsigned short)(cnt < (unsigned)CAP ? cnt : (unsigned)CAP);
  __syncthreads();

  // phase 3 (wave 0 only, lane = query): locked np-f32 exact selection (R4-verified logic)
  if (tid < 64) {
    const int nself = (q & (NPT - 1));
#pragma unroll
    for (int j = 0; j < 16; ++j) outs[l][j] = nself;

    float r[16];
#pragma unroll
    for (int i = 0; i < 16; ++i) r[i] = __builtin_inff();
#pragma unroll 1
    for (int w2 = 0; w2 < NSLICE; ++w2) {
      int cw = (int)scnt[w2][l];
      for (int i = 0; i < cw; ++i) {
        int m = (int)cand[(w2 * 64 + l) * CAP + i];
        float d = dist2np(qp, cb[m]);
        if (d < r[15]) {
          float prev = -__builtin_inff();
#pragma unroll
          for (int j = 0; j < 16; ++j) {
            float rj = r[j];
            r[j] = fminf(fmaxf(prev, d), rj);
            prev = rj;
          }
        }
      }
    }
    const float T = r[15];

    // pass 2: d<T (ascending index order) from the front; ties d==T fill from
    // the back (earliest-index ties win; consumer is a max, order irrelevant).
    int front = 0, tie_i = 0;
#pragma unroll 1
    for (int w2 = 0; w2 < NSLICE; ++w2) {
      int cw = (int)scnt[w2][l];
      for (int i = 0; i < cw; ++i) {
        int m = (int)cand[(w2 * 64 + l) * CAP + i];
        float d = dist2np(qp, cb[m]);
        if (d < T) {
          outs[l][front] = m;
          front++;
        } else if (d == T) {
          int pos = 15 - tie_i;
          if (pos >= front) outs[l][pos] = m;
          tie_i++;
        }
      }
    }
#pragma unroll
    for (int j = 0; j < 16; ++j) idxout[(size_t)q * 16 + j] = outs[l][j];
  }
}

// ---------------- bf16 MFMA GEMM: Qf32[32768,256] x WbT[512,256]^T -> A16 bf16 (n<256), Qn=d_out f32 (n>=256,+bias)
#define ASTRIDE 40   // LDS row stride in bf16 elems (80 B, 16B-aligned)
__global__ __launch_bounds__(256) void gemm_kernel(
    const float* __restrict__ Q, const unsigned short* __restrict__ WbT,
    const float* __restrict__ bias,
    unsigned short* __restrict__ A16, float* __restrict__ Qn)
{
  __shared__ __align__(16) unsigned short As[128 * ASTRIDE];
  __shared__ __align__(16) unsigned short Bs[128 * ASTRIDE];
  const int tid  = threadIdx.x;
  const int lane = tid & 63;
  const int wv   = tid >> 6;
  const int wr   = wv & 1, wc = wv >> 1;
  const int bm0  = blockIdx.x * 128;
  const int bn0  = blockIdx.y * 128;
  const int srow = tid >> 1;
  const int skh  = tid & 1;
  const int quad = lane >> 4;
  const int l15  = lane & 15;

  f32x4 acc[4][4];
#pragma unroll
  for (int i = 0; i < 4; ++i)
#pragma unroll
    for (int j = 0; j < 4; ++j) acc[i][j] = (f32x4)0.0f;

  const float* ag = Q + (size_t)(bm0 + srow) * 256 + skh * 16;
  const unsigned short* bg = WbT + (size_t)(bn0 + srow) * 256 + skh * 16;
  unsigned short* asw = &As[srow * ASTRIDE + skh * 16];
  unsigned short* bsw = &Bs[srow * ASTRIDE + skh * 16];

  for (int k0 = 0; k0 < 256; k0 += 32) {
    float4 f0 = *(const float4*)(ag + k0);
    float4 f1 = *(const float4*)(ag + k0 + 4);
    float4 f2 = *(const float4*)(ag + k0 + 8);
    float4 f3 = *(const float4*)(ag + k0 + 12);
    uint4 bv0 = *(const uint4*)(bg + k0);        // k-local [0,8)
    uint4 bv1 = *(const uint4*)(bg + k0 + 8);    // k-local [8,16)
    uint4 a0, a1;
    a0.x = pk_bf16(f0.x, f0.y); a0.y = pk_bf16(f0.z, f0.w);
    a0.z = pk_bf16(f1.x, f1.y); a0.w = pk_bf16(f1.z, f1.w);
    a1.x = pk_bf16(f2.x, f2.y); a1.y = pk_bf16(f2.z, f2.w);
    a1.z = pk_bf16(f3.x, f3.y); a1.w = pk_bf16(f3.z, f3.w);
    __syncthreads();
    *(uint4*)(asw) = a0;
    *(uint4*)(asw + 8) = a1;
    *(uint4*)(bsw) = bv0;
    *(uint4*)(bsw + 8) = bv1;
    __syncthreads();

    bf16x8 af[4], bf[4];
#pragma unroll
    for (int rt = 0; rt < 4; ++rt)
      af[rt] = *(const bf16x8*)&As[(wr * 64 + rt * 16 + l15) * ASTRIDE + quad * 8];
#pragma unroll
    for (int ct = 0; ct < 4; ++ct)
      bf[ct] = *(const bf16x8*)&Bs[(wc * 64 + ct * 16 + l15) * ASTRIDE + quad * 8];
#pragma unroll
    for (int rt = 0; rt < 4; ++rt)
#pragma unroll
      for (int ct = 0; ct < 4; ++ct)
        acc[rt][ct] = __builtin_amdgcn_mfma_f32_16x16x32_bf16(af[rt], bf[ct], acc[rt][ct], 0, 0, 0);
  }

  // epilogue: C/D layout col=lane&15, row=quad*4+reg (verified m89/m91)
  if (bn0 < 256) {
#pragma unroll
    for (int ct = 0; ct < 4; ++ct) {
      int col = bn0 + wc * 64 + ct * 16 + l15;
#pragma unroll
      for (int rt = 0; rt < 4; ++rt) {
        int rowb = bm0 + wr * 64 + rt * 16 + quad * 4;
#pragma unroll
        for (int r = 0; r < 4; ++r) {
          __hip_bfloat16 hb = __float2bfloat16(acc[rt][ct][r]);
          A16[(size_t)(rowb + r) * 256 + col] = *(unsigned short*)&hb;
        }
      }
    }
  } else {
#pragma unroll
    for (int ct = 0; ct < 4; ++ct) {
      int col = bn0 + wc * 64 + ct * 16 + l15 - 256;
      float bvl = bias[col];
#pragma unroll
      for (int rt = 0; rt < 4; ++rt) {
        int rowb = bm0 + wr * 64 + rt * 16 + quad * 4;
#pragma unroll
        for (int r = 0; r < 4; ++r)
          Qn[(size_t)(rowb + r) * 256 + col] = acc[rt][ct][r] + bvl;
      }
    }
  }
}

// ---------------- gather + leaky + max; Out holds Qn on entry, overwritten with result
__global__ __launch_bounds__(256) void gather_kernel(
    const unsigned short* __restrict__ A16, const int* __restrict__ idxout,
    float* __restrict__ Out)
{
  __shared__ int sidx[16];
  const int q = blockIdx.x;
  const int b = q >> 13;
  const int c = threadIdx.x;
  if (c < 16) sidx[c] = idxout[(size_t)q * 16 + c];
  __syncthreads();
  const float qn = Out[(size_t)q * 256 + c];
  const unsigned short* __restrict__ Ab = A16 + (size_t)b * NPT * 256;
  float best = -__builtin_inff();
#pragma unroll
  for (int j = 0; j < 16; ++j) {
    unsigned short raw = Ab[(size_t)sidx[j] * 256 + c];
    float a = __uint_as_float((unsigned)raw << 16);   // bf16 -> f32
    float h = a + qn;
    best = fmaxf(best, fmaxf(h, 0.2f * h));   // leaky_relu(h, 0.2) == max(h, 0.2h)
  }
  Out[(size_t)q * 256 + c] = best;
}

extern "C" void kernel_launch(void* const* d_in, const int* in_sizes, int n_in,
                              void* d_out, int out_size, void* d_ws, size_t ws_size,
                              hipStream_t stream)
{
  (void)in_sizes; (void)n_in; (void)out_size; (void)ws_size;
  const float* qf   = (const float*)d_in[0];
  const float* qpos = (const float*)d_in[1];
  const float* W    = (const float*)d_in[2];
  const float* bias = (const float*)d_in[3];

  char* ws = (char*)d_ws;
  size_t off = 0;
  auto alloc = [&](size_t bytes) {
    void* p = ws + off;
    off += (bytes + 255) & ~(size_t)255;
    return p;
  };
  float4* cpack       = (float4*)alloc((size_t)BN_TOT * sizeof(float4));       // 512 KB
  unsigned short* WbT = (unsigned short*)alloc((size_t)512 * 256 * 2);         // 256 KB
  int* idxout         = (int*)alloc((size_t)BN_TOT * KNN * sizeof(int));       // 2 MB
  unsigned short* A16 = (unsigned short*)alloc((size_t)BN_TOT * CH * 2);       // 16 MB
  float* Out          = (float*)d_out;                                         // Qn then result

  prep_kernel<<<512, 256, 0, stream>>>(qpos, W, cpack, WbT);
  knn_kernel<<<dim3(128, BATCH), 1024, 0, stream>>>(cpack, idxout);
  gemm_kernel<<<dim3(256, 4), 256, 0, stream>>>(qf, WbT, bias, A16, Out);
  gather_kernel<<<BN_TOT, 256, 0, stream>>>(A16, idxout, Out);
}